// Round 3
// baseline (698.870 us; speedup 1.0000x reference)
//
#include <hip/hip_runtime.h>
#include <math.h>

#define H 128
#define K 20
#define EPB 8   // edges per block

// ---- workspace layout (float offsets) ----
#define WS_TBLP  0            // 129 rows x 128 d x {W,B}
#define WS_TBLN  33024        // 129 rows x 128 d x {W,B}
#define WS_THP   66048        // 128 sorted thresholds (pos-w1 group)
#define WS_THN   66176        // 128 sorted thresholds (neg-w1 group)
#define WS_BASE  66304        // 128: tp_b2 + zero-w1 active contrib
#define WS_CNT   66432        // 2 ints: nP, nN
#define WS_SIDXP 66434        // 128 ints: sorted original indices (P)
#define WS_SIDXN 66562        // 128 ints: sorted original indices (N)

// DPP-based wave64 sum; result valid in lanes 48-63 (use readlane 63).
template<int CTRL, int RMASK>
__device__ __forceinline__ float dpp_add(float x) {
  int y = __builtin_amdgcn_update_dpp(0, __float_as_int(x), CTRL, RMASK, 0xf, true);
  return x + __int_as_float(y);
}
__device__ __forceinline__ float wave_sum63(float x) {
  x = dpp_add<0xB1,  0xf>(x);   // quad_perm [1,0,3,2]  (xor 1)
  x = dpp_add<0x4E,  0xf>(x);   // quad_perm [2,3,0,1]  (xor 2)
  x = dpp_add<0x141, 0xf>(x);   // row_half_mirror      (xor-ish 4)
  x = dpp_add<0x140, 0xf>(x);   // row_mirror           (xor-ish 8)
  x = dpp_add<0x142, 0xa>(x);   // row_bcast15 -> rows 1,3
  x = dpp_add<0x143, 0xc>(x);   // row_bcast31 -> rows 2,3
  return x;
}
__device__ __forceinline__ float bcast63(float x) {
  return __int_as_float(__builtin_amdgcn_readlane(__float_as_int(x), 63));
}

// Kernel 1: classify h by sign(w1), sort thresholds -b1/w1 per group.
__global__ __launch_bounds__(128) void build_sort_kernel(
    const float* __restrict__ w1, const float* __restrict__ b1,
    const float* __restrict__ w2, const float* __restrict__ b2,
    float* __restrict__ ws)
{
  __shared__ float th[H];
  __shared__ int grp[H];
  __shared__ int nP_s, nN_s;
  int h = threadIdx.x;
  float w = w1[h], b = b1[h];
  int g = (w > 0.f) ? 0 : ((w < 0.f) ? 1 : 2);
  float t = (g == 2) ? 0.f : (-b / w);
  th[h] = t; grp[h] = g;
  if (h == 0) { nP_s = 0; nN_s = 0; }
  __syncthreads();
  int* sidxP = (int*)(ws + WS_SIDXP);
  int* sidxN = (int*)(ws + WS_SIDXN);
  if (g == 0) {
    int r = 0;
    for (int i = 0; i < H; i++)
      if (grp[i] == 0 && (th[i] < t || (th[i] == t && i < h))) r++;
    sidxP[r] = h; ws[WS_THP + r] = t;
    atomicAdd(&nP_s, 1);
  } else if (g == 1) {
    int r = 0;
    for (int i = 0; i < H; i++)
      if (grp[i] == 1 && (th[i] < t || (th[i] == t && i < h))) r++;
    sidxN[r] = h; ws[WS_THN + r] = t;
    atomicAdd(&nN_s, 1);
  }
  float base = b2[h];
  for (int i = 0; i < H; i++)
    if (grp[i] == 2 && b1[i] > 0.f) base += b1[i] * w2[i * H + h];
  ws[WS_BASE + h] = base;
  __syncthreads();
  if (h == 0) {
    ((int*)(ws + WS_CNT))[0] = nP_s;
    ((int*)(ws + WS_CNT))[1] = nN_s;
  }
}

// Kernel 2: one block per table row; prefix/suffix sums per row.
__global__ __launch_bounds__(128) void build_rows_kernel(
    const float* __restrict__ w1v, const float* __restrict__ b1v,
    const float* __restrict__ w2, float* __restrict__ ws)
{
  int r = blockIdx.x;       // 0..128 = P rows, 129..257 = N rows
  int d = threadIdx.x;
  const int* cnt = (const int*)(ws + WS_CNT);
  int nP = cnt[0], nN = cnt[1];
  if (r <= 128) {
    if (r > nP) return;
    const int* sidx = (const int*)(ws + WS_SIDXP);
    float accW = 0.f, accB = ws[WS_BASE + d];
    for (int i = 0; i < r; i++) {
      int idx = sidx[i];
      float wv = w2[idx * H + d];
      accW += w1v[idx] * wv;
      accB += b1v[idx] * wv;
    }
    ws[WS_TBLP + (r * H + d) * 2 + 0] = accW;
    ws[WS_TBLP + (r * H + d) * 2 + 1] = accB;
  } else {
    int rr = r - 129;
    if (rr > nN) return;
    const int* sidx = (const int*)(ws + WS_SIDXN);
    float accW = 0.f, accB = 0.f;
    for (int i = rr; i < nN; i++) {
      int idx = sidx[i];
      float wv = w2[idx * H + d];
      accW += w1v[idx] * wv;
      accB += b1v[idx] * wv;
    }
    ws[WS_TBLN + (rr * H + d) * 2 + 0] = accW;
    ws[WS_TBLN + (rr * H + d) * 2 + 1] = accB;
  }
}

// Main fused kernel: 4 waves/block, wave owns an edge-side end-to-end.
// Lane holds dims 2*lane, 2*lane+1. Scalar pipe carries per-k control
// (readlane + ballot-rank -> SGPR table bases); DPP carries reductions.
__global__ __launch_bounds__(256, 4) void tgat_main_kernel(
    const int* __restrict__ edge_index, const int* __restrict__ edge_ts,
    const int* __restrict__ hist_nb, const int* __restrict__ hist_tm,
    const int* __restrict__ hist_sg,
    const float* __restrict__ node_emb, const float* __restrict__ sign_emb,
    const float* __restrict__ em_w1, const float* __restrict__ em_b1,
    const float* __restrict__ em_w2, const float* __restrict__ em_b2,
    const float* __restrict__ ws, float* __restrict__ out, int B)
{
  __shared__ __align__(16) float feat[EPB][4 * H];   // reused as hpart later

  int tid = threadIdx.x;
  int lane = tid & 63;
  int wv = tid >> 6;
  int b0 = blockIdx.x * EPB;

  const int* cnt = (const int*)(ws + WS_CNT);
  int nP = cnt[0], nN = cnt[1];
  float thP0 = (lane      < nP) ? ws[WS_THP + lane]      : 3.0e38f;
  float thP1 = (lane + 64 < nP) ? ws[WS_THP + lane + 64] : 3.0e38f;
  float thN0 = (lane      < nN) ? ws[WS_THN + lane]      : 3.0e38f;
  float thN1 = (lane + 64 < nN) ? ws[WS_THN + lane + 64] : 3.0e38f;
  float2 se0 = *(const float2*)(sign_emb + 2 * lane);
  float2 se1 = *(const float2*)(sign_emb + H + 2 * lane);

  #pragma unroll 1
  for (int i = 0; i < 4; i++) {
    int s = wv * 4 + i;              // edge-side id within block
    int e = s >> 1, side = s & 1;
    int b = b0 + e;
    if (b < B) {                     // wave-uniform
      int node = edge_index[side * B + b];
      int t = edge_ts[b];
      float2 q = *(const float2*)(node_emb + (size_t)node * H + 2 * lane);
      int pk_r = 0, tm_r = 0;
      if (lane < K) {
        int nb = hist_nb[node * K + lane];
        int sg = hist_sg[node * K + lane];
        tm_r = hist_tm[node * K + lane];
        pk_r = (nb << 1) | sg;
      }
      float key0[K], key1[K], sc[K];
      #pragma unroll
      for (int k = 0; k < K; k++) {
        int tm_k = __builtin_amdgcn_readlane(tm_r, k);   // scalar
        int pk_k = __builtin_amdgcn_readlane(pk_r, k);   // scalar
        int nb_k = pk_k >> 1;
        int sg_k = pk_k & 1;
        float dk = (float)t - (float)tm_k;               // uniform
        int rP = __popcll(__ballot(thP0 < dk)) + __popcll(__ballot(thP1 < dk));
        int rN = __popcll(__ballot(thN0 < dk)) + __popcll(__ballot(thN1 < dk));
        const float4 pw = *(const float4*)(ws + WS_TBLP + rP * (2 * H) + 4 * lane);
        const float4 nw = *(const float4*)(ws + WS_TBLN + rN * (2 * H) + 4 * lane);
        int nbc = (nb_k < 0) ? 0 : nb_k;
        float2 ne = *(const float2*)(node_emb + (size_t)nbc * H + 2 * lane);
        float te0 = dk * (pw.x + nw.x) + (pw.y + nw.y);
        float te1 = dk * (pw.z + nw.z) + (pw.w + nw.w);
        float k0 = ne.x + (sg_k ? se1.x : se0.x) + te0;
        float k1 = ne.y + (sg_k ? se1.y : se0.y) + te1;
        key0[k] = k0; key1[k] = k1;
        float p = wave_sum63(q.x * k0 + q.y * k1);
        float ps = bcast63(p);                           // uniform score
        bool valid = (nb_k != -1) && (tm_k < t);         // scalar
        sc[k] = valid ? ps * 0.088388347648318447f : -1e9f;
      }
      float mx = sc[0];
      #pragma unroll
      for (int k = 1; k < K; k++) mx = fmaxf(mx, sc[k]);
      float ssum = 0.f;
      #pragma unroll
      for (int k = 0; k < K; k++) { float ev = __expf(sc[k] - mx); sc[k] = ev; ssum += ev; }
      float inv = 1.f / ssum;
      float z0 = 0.f, z1 = 0.f;
      #pragma unroll
      for (int k = 0; k < K; k++) {
        float a = sc[k] * inv;                           // uniform
        z0 += a * key0[k];
        z1 += a * key1[k];
      }
      *(float2*)&feat[e][side * H + 2 * lane] = make_float2(z0, z1);
    }
  }
  __syncthreads();

  // derived feature columns: |zu-zv|, zu*zv
  for (int j = tid; j < EPB * H; j += 256) {
    int e = j >> 7, d = j & 127;
    float a = feat[e][d], c = feat[e][H + d];
    feat[e][2 * H + d] = fabsf(a - c);
    feat[e][3 * H + d] = a * c;
  }
  __syncthreads();

  // ---- final MLP: thread owns dims (2*d2, 2*d2+1) x 8 edges, i-quarter qtr.
  int d2 = tid & 63;
  int qtr = tid >> 6;
  float acc0[EPB], acc1[EPB];
  #pragma unroll
  for (int e = 0; e < EPB; e++) { acc0[e] = 0.f; acc1[e] = 0.f; }
  const float* w1c = em_w1 + 2 * d2;
  for (int ii = qtr * 128; ii < qtr * 128 + 128; ii += 4) {
    float2 wA = *(const float2*)(w1c + (ii + 0) * H);
    float2 wB = *(const float2*)(w1c + (ii + 1) * H);
    float2 wC = *(const float2*)(w1c + (ii + 2) * H);
    float2 wD = *(const float2*)(w1c + (ii + 3) * H);
    #pragma unroll
    for (int e = 0; e < EPB; e++) {
      float4 f = *(const float4*)&feat[e][ii];   // uniform addr -> broadcast
      acc0[e] += f.x * wA.x + f.y * wB.x + f.z * wC.x + f.w * wD.x;
      acc1[e] += f.x * wA.y + f.y * wB.y + f.z * wC.y + f.w * wD.y;
    }
  }
  __syncthreads();                  // everyone done reading feat
  float* hp = &feat[0][0];          // reuse LDS: hp[qtr*1024 + e*128 + d]
  #pragma unroll
  for (int e = 0; e < EPB; e++)
    *(float2*)(hp + qtr * 1024 + e * 128 + 2 * d2) = make_float2(acc0[e], acc1[e]);
  __syncthreads();

  // each wave finishes 2 edges
  #pragma unroll
  for (int ei = 0; ei < 2; ei++) {
    int e = wv * 2 + ei;
    int b = b0 + e;
    float h0 = hp[e * 128 + lane]        + hp[1024 + e * 128 + lane]
             + hp[2048 + e * 128 + lane] + hp[3072 + e * 128 + lane] + em_b1[lane];
    float h1 = hp[e * 128 + lane + 64]        + hp[1024 + e * 128 + lane + 64]
             + hp[2048 + e * 128 + lane + 64] + hp[3072 + e * 128 + lane + 64] + em_b1[lane + 64];
    h0 = fmaxf(h0, 0.f); h1 = fmaxf(h1, 0.f);
    float p = wave_sum63(h0 * em_w2[lane] + h1 * em_w2[lane + 64]);
    float ps = bcast63(p);
    if (lane == 0 && b < B) out[b] = ps + em_b2[0];
  }
}

extern "C" void kernel_launch(void* const* d_in, const int* in_sizes, int n_in,
                              void* d_out, int out_size, void* d_ws, size_t ws_size,
                              hipStream_t stream)
{
  (void)n_in; (void)out_size; (void)ws_size;
  const int* edge_index = (const int*)d_in[0];
  const int* edge_ts    = (const int*)d_in[1];
  const int* hist_nb    = (const int*)d_in[2];
  const int* hist_tm    = (const int*)d_in[3];
  const int* hist_sg    = (const int*)d_in[4];
  const float* node_emb = (const float*)d_in[5];
  const float* sign_emb = (const float*)d_in[6];
  const float* tp_w1    = (const float*)d_in[7];
  const float* tp_b1    = (const float*)d_in[8];
  const float* tp_w2    = (const float*)d_in[9];
  const float* tp_b2    = (const float*)d_in[10];
  const float* em_w1    = (const float*)d_in[11];
  const float* em_b1    = (const float*)d_in[12];
  const float* em_w2    = (const float*)d_in[13];
  const float* em_b2    = (const float*)d_in[14];
  float* out = (float*)d_out;
  float* ws  = (float*)d_ws;
  int B = in_sizes[1];

  hipLaunchKernelGGL(build_sort_kernel, dim3(1), dim3(H), 0, stream,
                     tp_w1, tp_b1, tp_w2, tp_b2, ws);
  hipLaunchKernelGGL(build_rows_kernel, dim3(258), dim3(H), 0, stream,
                     tp_w1, tp_b1, tp_w2, ws);
  int grid = (B + EPB - 1) / EPB;
  hipLaunchKernelGGL(tgat_main_kernel, dim3(grid), dim3(256), 0, stream,
                     edge_index, edge_ts, hist_nb, hist_tm, hist_sg,
                     node_emb, sign_emb, em_w1, em_b1, em_w2, em_b2, ws, out, B);
}

// Round 4
// 483.826 us; speedup vs baseline: 1.4445x; 1.4445x over previous
//
#include <hip/hip_runtime.h>
#include <math.h>

#define H 128
#define K 20
#define EPB 8   // edges per block

// ---- workspace layout (float offsets) ----
// Merged table: 257 rows x 128 dims x {W,B} interleaved as [W0,B0,W1,B1,...]
#define WS_TBL    0            // 257 * 256 floats
#define WS_THM    65792        // 256 merged sorted thresholds
#define WS_BASE   66048        // 128: tp_b2 + zero-w1 active contrib
#define WS_CNT    66176        // 1 int: M = nP + nN
#define WS_SIDXM  66177        // 256 ints: (h<<1)|isP in merged sorted order

// DPP-based wave64 sum; result valid in lane 63.
template<int CTRL, int RMASK>
__device__ __forceinline__ float dpp_add(float x) {
  int y = __builtin_amdgcn_update_dpp(0, __float_as_int(x), CTRL, RMASK, 0xf, true);
  return x + __int_as_float(y);
}
__device__ __forceinline__ float wave_sum63(float x) {
  x = dpp_add<0xB1,  0xf>(x);   // quad_perm [1,0,3,2]
  x = dpp_add<0x4E,  0xf>(x);   // quad_perm [2,3,0,1]
  x = dpp_add<0x141, 0xf>(x);   // row_half_mirror
  x = dpp_add<0x140, 0xf>(x);   // row_mirror
  x = dpp_add<0x142, 0xa>(x);   // row_bcast15 -> rows 1,3
  x = dpp_add<0x143, 0xc>(x);   // row_bcast31 -> rows 2,3
  return x;
}
__device__ __forceinline__ float bcast63(float x) {
  return __int_as_float(__builtin_amdgcn_readlane(__float_as_int(x), 63));
}

// Kernel 1: classify h by sign(w1); merged rank of -b1/w1 across P and N.
__global__ __launch_bounds__(128) void build_sort_kernel(
    const float* __restrict__ w1, const float* __restrict__ b1,
    const float* __restrict__ w2, const float* __restrict__ b2,
    float* __restrict__ ws)
{
  __shared__ float th[H];
  __shared__ int grp[H];
  int h = threadIdx.x;
  float w = w1[h], b = b1[h];
  int g = (w > 0.f) ? 0 : ((w < 0.f) ? 1 : 2);   // 0=P, 1=N, 2=Z
  float t = (g == 2) ? 0.f : (-b / w);
  th[h] = t; grp[h] = g;
  __syncthreads();
  int* sidxM = (int*)(ws + WS_SIDXM);
  if (g != 2) {
    int r = 0;
    for (int i = 0; i < H; i++)
      if (grp[i] != 2 && (th[i] < t || (th[i] == t && i < h))) r++;
    sidxM[r] = (h << 1) | (g == 0 ? 1 : 0);
    ws[WS_THM + r] = t;
  }
  // BASE[d] = tp_b2[d] + sum over (w1==0, b1>0) of b1*w2[h][d]
  float base = b2[h];
  for (int i = 0; i < H; i++)
    if (grp[i] == 2 && b1[i] > 0.f) base += b1[i] * w2[i * H + h];
  ws[WS_BASE + h] = base;
  if (h == 0) {
    int M = 0;
    for (int i = 0; i < H; i++) if (grp[i] != 2) M++;
    ((int*)(ws + WS_CNT))[0] = M;
  }
}

// Kernel 2: one block per merged-table row r in [0, M]:
// W[r] = sum_{i<r, P} w1*w2 + sum_{i>=r, N} w1*w2 ; B[r] analog + BASE.
__global__ __launch_bounds__(128) void build_rows_kernel(
    const float* __restrict__ w1v, const float* __restrict__ b1v,
    const float* __restrict__ w2, float* __restrict__ ws)
{
  int r = blockIdx.x;
  int d = threadIdx.x;
  int M = ((const int*)(ws + WS_CNT))[0];
  if (r > M) return;
  const int* sidxM = (const int*)(ws + WS_SIDXM);
  float accW = 0.f, accB = ws[WS_BASE + d];
  for (int i = 0; i < M; i++) {
    int ent = sidxM[i];
    int h = ent >> 1;
    int isP = ent & 1;
    int take = (i < r) ? isP : (1 - isP);
    if (take) {
      float wv = w2[h * H + d];
      accW += w1v[h] * wv;
      accB += b1v[h] * wv;
    }
  }
  ws[WS_TBL + r * 256 + 2 * d + 0] = accW;
  ws[WS_TBL + r * 256 + 2 * d + 1] = accB;
}

// Main fused kernel: 4 waves/block, wave owns 4 edge-sides sequentially
// (lane holds dims 2*lane, 2*lane+1). Online softmax; all 20 node_emb
// gathers prefetched into registers; 1-deep pipeline across sides.
__global__ __launch_bounds__(256, 4) void tgat_main_kernel(
    const int* __restrict__ edge_index, const int* __restrict__ edge_ts,
    const int* __restrict__ hist_nb, const int* __restrict__ hist_tm,
    const int* __restrict__ hist_sg,
    const float* __restrict__ node_emb, const float* __restrict__ sign_emb,
    const float* __restrict__ em_w1, const float* __restrict__ em_b1,
    const float* __restrict__ em_w2, const float* __restrict__ em_b2,
    const float* __restrict__ ws, float* __restrict__ out, int B)
{
  __shared__ __align__(16) float feat[EPB][4 * H];   // reused as hpart later

  int tid = threadIdx.x;
  int lane = tid & 63;
  int wv = __builtin_amdgcn_readfirstlane(tid >> 6);
  int b0 = blockIdx.x * EPB;

  int M = ((const int*)(ws + WS_CNT))[0];
  float th0 = (lane       < M) ? ws[WS_THM + lane      ] : 3.0e38f;
  float th1 = (lane + 64  < M) ? ws[WS_THM + lane + 64 ] : 3.0e38f;
  float th2 = (lane + 128 < M) ? ws[WS_THM + lane + 128] : 3.0e38f;
  float th3 = (lane + 192 < M) ? ws[WS_THM + lane + 192] : 3.0e38f;
  float2 se0 = *(const float2*)(sign_emb + 2 * lane);
  float2 se1 = *(const float2*)(sign_emb + H + 2 * lane);

  // ---- prefetch side 0 of this wave ----
  int sbase = wv * 4;
  {
  }
  int e_n = (sbase) >> 1, side_n = sbase & 1;
  int node = edge_index[side_n * B + (b0 + e_n)];
  int t_n = edge_ts[b0 + e_n];
  float2 q_n = *(const float2*)(node_emb + (size_t)node * H + 2 * lane);
  int pk_n = 0, tm_n = 0;
  if (lane < K) {
    int nb = hist_nb[node * K + lane];
    int sg = hist_sg[node * K + lane];
    tm_n = hist_tm[node * K + lane];
    pk_n = (nb << 1) | sg;
  }

  #pragma unroll 1
  for (int i = 0; i < 4; i++) {
    int s = sbase + i;
    int e = s >> 1, side = s & 1;
    // current side's data
    int tC = t_n; float2 qC = q_n; int pkC = pk_n, tmC = tm_n;
    // prefetch next side
    if (i < 3) {
      int s2 = s + 1;
      int e2 = s2 >> 1, side2 = s2 & 1;
      int node2 = edge_index[side2 * B + (b0 + e2)];
      t_n = edge_ts[b0 + e2];
      q_n = *(const float2*)(node_emb + (size_t)node2 * H + 2 * lane);
      if (lane < K) {
        int nb = hist_nb[node2 * K + lane];
        int sg = hist_sg[node2 * K + lane];
        tm_n = hist_tm[node2 * K + lane];
        pk_n = (nb << 1) | sg;
      }
    }

    // ---- prefetch all K neighbor-embedding rows into registers ----
    float2 ne[K];
    #pragma unroll
    for (int k = 0; k < K; k++) {
      int pk_k = __builtin_amdgcn_readlane(pkC, k);
      int nbc = (pk_k < 0) ? 0 : (pk_k >> 1);
      ne[k] = *(const float2*)(node_emb + (size_t)nbc * H + 2 * lane);
    }

    // ---- online-softmax attention over K ----
    float m = -3.0e38f, ssum = 0.f, z0 = 0.f, z1 = 0.f;
    #pragma unroll
    for (int k = 0; k < K; k++) {
      int tm_k = __builtin_amdgcn_readlane(tmC, k);
      int pk_k = __builtin_amdgcn_readlane(pkC, k);
      int sg_k = pk_k & 1;
      float dk = (float)tC - (float)tm_k;                 // uniform
      int r = __popcll(__ballot(th0 < dk)) + __popcll(__ballot(th1 < dk))
            + __popcll(__ballot(th2 < dk)) + __popcll(__ballot(th3 < dk));
      const float4 tb = *(const float4*)(ws + WS_TBL + r * 256 + 4 * lane);
      float k0 = ne[k].x + (sg_k ? se1.x : se0.x) + dk * tb.x + tb.y;
      float k1 = ne[k].y + (sg_k ? se1.y : se0.y) + dk * tb.z + tb.w;
      float p = wave_sum63(qC.x * k0 + qC.y * k1);
      float ps = bcast63(p) * 0.088388347648318447f;      // 1/sqrt(128)
      bool valid = (pk_k >= 0) && (tm_k < tC);
      float sck = valid ? ps : -1e9f;
      float mn = fmaxf(m, sck);
      float al = __expf(m - mn);
      float pe = __expf(sck - mn);
      ssum = ssum * al + pe;
      z0 = z0 * al + pe * k0;
      z1 = z1 * al + pe * k1;
      m = mn;
    }
    float inv = 1.f / ssum;
    *(float2*)&feat[e][side * H + 2 * lane] = make_float2(z0 * inv, z1 * inv);
  }
  __syncthreads();

  // derived feature columns: |zu-zv|, zu*zv
  for (int j = tid; j < EPB * H; j += 256) {
    int e = j >> 7, d = j & 127;
    float a = feat[e][d], c = feat[e][H + d];
    feat[e][2 * H + d] = fabsf(a - c);
    feat[e][3 * H + d] = a * c;
  }
  __syncthreads();

  // ---- final MLP: thread owns dims (2*d2, 2*d2+1) x 8 edges, i-quarter qtr.
  int d2 = tid & 63;
  int qtr = tid >> 6;
  float acc0[EPB], acc1[EPB];
  #pragma unroll
  for (int e = 0; e < EPB; e++) { acc0[e] = 0.f; acc1[e] = 0.f; }
  const float* w1c = em_w1 + 2 * d2;
  for (int ii = qtr * 128; ii < qtr * 128 + 128; ii += 4) {
    float2 wA = *(const float2*)(w1c + (ii + 0) * H);
    float2 wB = *(const float2*)(w1c + (ii + 1) * H);
    float2 wC = *(const float2*)(w1c + (ii + 2) * H);
    float2 wD = *(const float2*)(w1c + (ii + 3) * H);
    #pragma unroll
    for (int e = 0; e < EPB; e++) {
      float4 f = *(const float4*)&feat[e][ii];   // uniform addr -> broadcast
      acc0[e] += f.x * wA.x + f.y * wB.x + f.z * wC.x + f.w * wD.x;
      acc1[e] += f.x * wA.y + f.y * wB.y + f.z * wC.y + f.w * wD.y;
    }
  }
  __syncthreads();                  // everyone done reading feat
  float* hp = &feat[0][0];          // reuse LDS: hp[qtr*1024 + e*128 + d]
  #pragma unroll
  for (int e = 0; e < EPB; e++)
    *(float2*)(hp + qtr * 1024 + e * 128 + 2 * d2) = make_float2(acc0[e], acc1[e]);
  __syncthreads();

  // each wave finishes 2 edges
  #pragma unroll
  for (int ei = 0; ei < 2; ei++) {
    int e = wv * 2 + ei;
    int b = b0 + e;
    float h0 = hp[e * 128 + lane]        + hp[1024 + e * 128 + lane]
             + hp[2048 + e * 128 + lane] + hp[3072 + e * 128 + lane] + em_b1[lane];
    float h1 = hp[e * 128 + lane + 64]        + hp[1024 + e * 128 + lane + 64]
             + hp[2048 + e * 128 + lane + 64] + hp[3072 + e * 128 + lane + 64] + em_b1[lane + 64];
    h0 = fmaxf(h0, 0.f); h1 = fmaxf(h1, 0.f);
    float p = wave_sum63(h0 * em_w2[lane] + h1 * em_w2[lane + 64]);
    float ps = bcast63(p);
    if (lane == 0 && b < B) out[b] = ps + em_b2[0];
  }
}

extern "C" void kernel_launch(void* const* d_in, const int* in_sizes, int n_in,
                              void* d_out, int out_size, void* d_ws, size_t ws_size,
                              hipStream_t stream)
{
  (void)n_in; (void)out_size; (void)ws_size;
  const int* edge_index = (const int*)d_in[0];
  const int* edge_ts    = (const int*)d_in[1];
  const int* hist_nb    = (const int*)d_in[2];
  const int* hist_tm    = (const int*)d_in[3];
  const int* hist_sg    = (const int*)d_in[4];
  const float* node_emb = (const float*)d_in[5];
  const float* sign_emb = (const float*)d_in[6];
  const float* tp_w1    = (const float*)d_in[7];
  const float* tp_b1    = (const float*)d_in[8];
  const float* tp_w2    = (const float*)d_in[9];
  const float* tp_b2    = (const float*)d_in[10];
  const float* em_w1    = (const float*)d_in[11];
  const float* em_b1    = (const float*)d_in[12];
  const float* em_w2    = (const float*)d_in[13];
  const float* em_b2    = (const float*)d_in[14];
  float* out = (float*)d_out;
  float* ws  = (float*)d_ws;
  int B = in_sizes[1];

  hipLaunchKernelGGL(build_sort_kernel, dim3(1), dim3(H), 0, stream,
                     tp_w1, tp_b1, tp_w2, tp_b2, ws);
  hipLaunchKernelGGL(build_rows_kernel, dim3(257), dim3(H), 0, stream,
                     tp_w1, tp_b1, tp_w2, ws);
  int grid = (B + EPB - 1) / EPB;
  hipLaunchKernelGGL(tgat_main_kernel, dim3(grid), dim3(256), 0, stream,
                     edge_index, edge_ts, hist_nb, hist_tm, hist_sg,
                     node_emb, sign_emb, em_w1, em_b1, em_w2, em_b2, ws, out, B);
}